// Round 1
// baseline (1169.587 us; speedup 1.0000x reference)
//
#include <hip/hip_runtime.h>

#define RPW 8  // rows per wave in the fused row kernels

// ---------------------------------------------------------------------------
// Histogram of row indices for A and X (counts land in curA/curX).
// ---------------------------------------------------------------------------
__global__ void hist_kernel(const int* __restrict__ Arow, int nA,
                            const int* __restrict__ Xrow, int nX,
                            int* __restrict__ cntA, int* __restrict__ cntX) {
    int i = blockIdx.x * 256 + threadIdx.x;
    if (i < nA) {
        atomicAdd(&cntA[Arow[i]], 1);
    } else if (i < nA + nX) {
        atomicAdd(&cntX[Xrow[i - nA]], 1);
    }
}

// ---------------------------------------------------------------------------
// Exclusive scan of counts -> row offsets. Block 0 scans A (n=V), block 1
// scans X (n=N_DOCS). Writes off[0..n] (off[i+1]=inclusive) and rewrites
// cnt[i] to the exclusive offset (becomes the scatter cursor).
// Wave-shuffle scan + tiny serial cross-wave combine: ~3 barriers per 1024.
// ---------------------------------------------------------------------------
__global__ __launch_bounds__(1024) void scan_kernel(int* cntA, int* offA, int nA,
                                                    int* cntX, int* offX, int nX) {
    int* cnt; int* off; int n;
    if (blockIdx.x == 0) { cnt = cntA; off = offA; n = nA; }
    else                 { cnt = cntX; off = offX; n = nX; }
    __shared__ int wsum[16];
    __shared__ int carry_s;
    int tid = threadIdx.x, lane = tid & 63, w = tid >> 6;
    if (tid == 0) { carry_s = 0; off[0] = 0; }
    __syncthreads();
    for (int base = 0; base < n; base += 1024) {
        int i = base + tid;
        int x = (i < n) ? cnt[i] : 0;
        int v = x;
        #pragma unroll
        for (int d = 1; d < 64; d <<= 1) {
            int t = __shfl_up(v, d);
            if (lane >= d) v += t;
        }
        if (lane == 63) wsum[w] = v;
        __syncthreads();
        if (tid == 0) {
            int a = carry_s;
            #pragma unroll
            for (int j = 0; j < 16; ++j) { int t = wsum[j]; wsum[j] = a; a += t; }
            carry_s = a;
        }
        __syncthreads();
        int incl = v + wsum[w];           // global inclusive prefix
        if (i < n) { off[i + 1] = incl; cnt[i] = incl - x; }
        __syncthreads();
    }
}

// ---------------------------------------------------------------------------
// Scatter COO -> CSR arrays using the cursor (counting sort by row).
// ---------------------------------------------------------------------------
__global__ void scatter_kernel(const int* __restrict__ Arow, const int* __restrict__ Acol,
                               const float* __restrict__ Aval, int nA,
                               const int* __restrict__ Xrow, const int* __restrict__ Xcol,
                               const float* __restrict__ Xval, int nX,
                               int* __restrict__ curA, int* __restrict__ scolA, float* __restrict__ svalA,
                               int* __restrict__ curX, int* __restrict__ scolX, float* __restrict__ svalX) {
    int i = blockIdx.x * 256 + threadIdx.x;
    if (i < nA) {
        int r = Arow[i];
        int p = atomicAdd(&curA[r], 1);
        scolA[p] = Acol[i];
        svalA[p] = Aval[i];
    } else if (i < nA + nX) {
        int j = i - nA;
        int r = Xrow[j];
        int p = atomicAdd(&curX[r], 1);
        scolX[p] = Xcol[j];
        svalX[p] = Xval[j];
    }
}

// ---------------------------------------------------------------------------
// Transpose the three 128x128 weight matrices so the per-row GEMM reads are
// coalesced: Wt[k][j] = W[j][k]  (out[j] = sum_k in[k]*Wt[k][j]).
// ---------------------------------------------------------------------------
__global__ void prep_kernel(const float* __restrict__ W1, const float* __restrict__ W2,
                            const float* __restrict__ W3,
                            float* __restrict__ Wt1, float* __restrict__ Wt2,
                            float* __restrict__ Wt3) {
    int gid = blockIdx.x * 256 + threadIdx.x;      // 0 .. 3*16384-1
    int m = gid >> 14;
    int idx = gid & 16383;
    int j = idx >> 7;
    int k = idx & 127;
    const float* W = (m == 0) ? W1 : (m == 1) ? W2 : W3;
    float*      Wt = (m == 0) ? Wt1 : (m == 1) ? Wt2 : Wt3;
    Wt[k * 128 + j] = W[j * 128 + k];
}

// ---------------------------------------------------------------------------
// Fused layer kernel. One wave owns RPW rows; lane l holds columns 2l,2l+1.
//   mode 0: out = relu(spmm(A,in) @ W^T)
//   mode 1: t = relu(spmm(A,in) @ W^T); u = 0.3*emb + 0.7*t;
//           out = layernorm(u)*g + b + emb        (word_H + emb_W, pre-fused)
// No __syncthreads in the hot path: LDS slices are wave-private.
// ---------------------------------------------------------------------------
__global__ __launch_bounds__(256) void layer_kernel(
    const int* __restrict__ off, const int* __restrict__ scol, const float* __restrict__ sval,
    const float2* __restrict__ in,            // [nrows][64] (float2 view of [.,128])
    const float2* __restrict__ Wt,            // [128][64]   (float2 view)
    const float2* __restrict__ emb,           // mode 1 only
    const float* __restrict__ g, const float* __restrict__ bb,  // mode 1 only
    float2* __restrict__ out, int nrows, int mode) {

    __shared__ float acc_s[4][RPW][128];
    int lane = threadIdx.x & 63;
    int wave = threadIdx.x >> 6;
    int rowbase = (blockIdx.x * 4 + wave) * RPW;

    // --- SpMM: gather-reduce each row into wave-private LDS ---
    for (int r = 0; r < RPW; ++r) {
        int row = rowbase + r;
        float2 a = make_float2(0.f, 0.f);
        if (row < nrows) {
            int s = off[row], e = off[row + 1];
            int i = s;
            for (; i + 1 < e; i += 2) {
                int c0 = scol[i], c1 = scol[i + 1];
                float v0 = sval[i], v1 = sval[i + 1];
                float2 x0 = in[(size_t)c0 * 64 + lane];
                float2 x1 = in[(size_t)c1 * 64 + lane];
                a.x += v0 * x0.x + v1 * x1.x;
                a.y += v0 * x0.y + v1 * x1.y;
            }
            if (i < e) {
                int c = scol[i];
                float v = sval[i];
                float2 x = in[(size_t)c * 64 + lane];
                a.x += v * x.x;
                a.y += v * x.y;
            }
        }
        *(float2*)&acc_s[wave][r][2 * lane] = a;
    }

    // --- dense 128x128 GEMM: o[r][j] = sum_k acc[r][k] * Wt[k][j] ---
    float2 o[RPW];
    #pragma unroll
    for (int r = 0; r < RPW; ++r) o[r] = make_float2(0.f, 0.f);
    for (int k = 0; k < 128; k += 2) {
        float2 w0 = Wt[(size_t)k * 64 + lane];
        float2 w1 = Wt[(size_t)(k + 1) * 64 + lane];
        #pragma unroll
        for (int r = 0; r < RPW; ++r) {
            float a0 = acc_s[wave][r][k];
            float a1 = acc_s[wave][r][k + 1];
            o[r].x += a0 * w0.x + a1 * w1.x;
            o[r].y += a0 * w0.y + a1 * w1.y;
        }
    }

    // --- epilogue ---
    for (int r = 0; r < RPW; ++r) {
        int row = rowbase + r;
        if (row >= nrows) break;
        float2 h = make_float2(fmaxf(o[r].x, 0.f), fmaxf(o[r].y, 0.f));
        if (mode == 0) {
            out[(size_t)row * 64 + lane] = h;
        } else {
            float2 e2 = emb[(size_t)row * 64 + lane];
            float2 u = make_float2(0.3f * e2.x + 0.7f * h.x,
                                   0.3f * e2.y + 0.7f * h.y);
            float s = u.x + u.y;
            #pragma unroll
            for (int d = 1; d < 64; d <<= 1) s += __shfl_xor(s, d);
            float mu = s * (1.f / 128.f);
            float dx = u.x - mu, dy = u.y - mu;
            float q = dx * dx + dy * dy;
            #pragma unroll
            for (int d = 1; d < 64; d <<= 1) q += __shfl_xor(q, d);
            float rstd = rsqrtf(q * (1.f / 128.f) + 1e-5f);
            float2 gg = *(const float2*)&g[2 * lane];
            float2 b2 = *(const float2*)&bb[2 * lane];
            float2 wv;
            wv.x = dx * rstd * gg.x + b2.x + e2.x;   // word_H + emb_W fused
            wv.y = dy * rstd * gg.y + b2.y + e2.y;
            out[(size_t)row * 64 + lane] = wv;
        }
    }
}

// ---------------------------------------------------------------------------
// Doc kernel: spmm(X, word_sum) -> relu(. @ mlp_W^T + mlp_b) -> clf logits.
// ---------------------------------------------------------------------------
__global__ __launch_bounds__(256) void doc_kernel(
    const int* __restrict__ off, const int* __restrict__ scol, const float* __restrict__ sval,
    const float2* __restrict__ in,            // word_sum [V][64]
    const float2* __restrict__ Wt,            // mlp_W transposed [128][64]
    const float* __restrict__ mlp_b, const float* __restrict__ clfW,
    const float* __restrict__ clfb,
    float* __restrict__ outp, int nrows) {

    __shared__ float acc_s[4][RPW][128];
    int lane = threadIdx.x & 63;
    int wave = threadIdx.x >> 6;
    int rowbase = (blockIdx.x * 4 + wave) * RPW;

    for (int r = 0; r < RPW; ++r) {
        int row = rowbase + r;
        float2 a = make_float2(0.f, 0.f);
        if (row < nrows) {
            int s = off[row], e = off[row + 1];
            int i = s;
            for (; i + 1 < e; i += 2) {
                int c0 = scol[i], c1 = scol[i + 1];
                float v0 = sval[i], v1 = sval[i + 1];
                float2 x0 = in[(size_t)c0 * 64 + lane];
                float2 x1 = in[(size_t)c1 * 64 + lane];
                a.x += v0 * x0.x + v1 * x1.x;
                a.y += v0 * x0.y + v1 * x1.y;
            }
            if (i < e) {
                int c = scol[i];
                float v = sval[i];
                float2 x = in[(size_t)c * 64 + lane];
                a.x += v * x.x;
                a.y += v * x.y;
            }
        }
        *(float2*)&acc_s[wave][r][2 * lane] = a;
    }

    float2 o[RPW];
    #pragma unroll
    for (int r = 0; r < RPW; ++r) o[r] = make_float2(0.f, 0.f);
    for (int k = 0; k < 128; k += 2) {
        float2 w0 = Wt[(size_t)k * 64 + lane];
        float2 w1 = Wt[(size_t)(k + 1) * 64 + lane];
        #pragma unroll
        for (int r = 0; r < RPW; ++r) {
            float a0 = acc_s[wave][r][k];
            float a1 = acc_s[wave][r][k + 1];
            o[r].x += a0 * w0.x + a1 * w1.x;
            o[r].y += a0 * w0.y + a1 * w1.y;
        }
    }

    float2 mb = *(const float2*)&mlp_b[2 * lane];
    float2 c0 = *(const float2*)&clfW[2 * lane];
    float2 c1 = *(const float2*)&clfW[128 + 2 * lane];
    for (int r = 0; r < RPW; ++r) {
        int row = rowbase + r;
        if (row >= nrows) break;
        float hx = fmaxf(o[r].x + mb.x, 0.f);
        float hy = fmaxf(o[r].y + mb.y, 0.f);
        float p0 = hx * c0.x + hy * c0.y;
        float p1 = hx * c1.x + hy * c1.y;
        #pragma unroll
        for (int d = 1; d < 64; d <<= 1) {
            p0 += __shfl_xor(p0, d);
            p1 += __shfl_xor(p1, d);
        }
        if (lane == 0) {
            outp[(size_t)row * 2 + 0] = p0 + clfb[0];
            outp[(size_t)row * 2 + 1] = p1 + clfb[1];
        }
    }
}

// ---------------------------------------------------------------------------
extern "C" void kernel_launch(void* const* d_in, const int* in_sizes, int n_in,
                              void* d_out, int out_size, void* d_ws, size_t ws_size,
                              hipStream_t stream) {
    const int*   A_row  = (const int*)d_in[0];
    const int*   A_col  = (const int*)d_in[1];
    const float* A_val  = (const float*)d_in[2];
    const int*   X_row  = (const int*)d_in[3];
    const int*   X_col  = (const int*)d_in[4];
    const float* X_val  = (const float*)d_in[5];
    const float* emb_W  = (const float*)d_in[6];
    const float* lin1_W = (const float*)d_in[7];
    const float* lin2_W = (const float*)d_in[8];
    const float* norm_g = (const float*)d_in[9];
    const float* norm_b = (const float*)d_in[10];
    const float* mlp_W  = (const float*)d_in[11];
    const float* mlp_b  = (const float*)d_in[12];
    const float* clf_W  = (const float*)d_in[13];
    const float* clf_b  = (const float*)d_in[14];

    const int E   = in_sizes[0];
    const int NNZ = in_sizes[3];
    const int V   = in_sizes[6] / 128;
    const int D   = out_size / 2;   // N_DOCS

    // workspace carve-up (256B aligned)
    char* p = (char*)d_ws;
    auto alloc = [&](size_t bytes) -> void* {
        void* q = (void*)p;
        p += (bytes + 255) & ~(size_t)255;
        return q;
    };
    int*   curA  = (int*)alloc((size_t)V * 4);
    int*   offA  = (int*)alloc((size_t)(V + 1) * 4);
    int*   scolA = (int*)alloc((size_t)E * 4);
    float* svalA = (float*)alloc((size_t)E * 4);
    int*   curX  = (int*)alloc((size_t)D * 4);
    int*   offX  = (int*)alloc((size_t)(D + 1) * 4);
    int*   scolX = (int*)alloc((size_t)NNZ * 4);
    float* svalX = (float*)alloc((size_t)NNZ * 4);
    float* Wt1   = (float*)alloc(128 * 128 * 4);
    float* Wt2   = (float*)alloc(128 * 128 * 4);
    float* Wt3   = (float*)alloc(128 * 128 * 4);
    float* H1    = (float*)alloc((size_t)V * 128 * 4);
    float* WS    = (float*)alloc((size_t)V * 128 * 4);   // word_H + emb_W

    hipMemsetAsync(curA, 0, (size_t)V * 4, stream);
    hipMemsetAsync(curX, 0, (size_t)D * 4, stream);

    int tot = E + NNZ;
    hist_kernel<<<(tot + 255) / 256, 256, 0, stream>>>(A_row, E, X_row, NNZ, curA, curX);
    scan_kernel<<<2, 1024, 0, stream>>>(curA, offA, V, curX, offX, D);
    scatter_kernel<<<(tot + 255) / 256, 256, 0, stream>>>(
        A_row, A_col, A_val, E, X_row, X_col, X_val, NNZ,
        curA, scolA, svalA, curX, scolX, svalX);
    prep_kernel<<<192, 256, 0, stream>>>(lin1_W, lin2_W, mlp_W, Wt1, Wt2, Wt3);

    int layer_blocks = (V + 4 * RPW - 1) / (4 * RPW);
    layer_kernel<<<layer_blocks, 256, 0, stream>>>(
        offA, scolA, svalA, (const float2*)emb_W, (const float2*)Wt1,
        nullptr, nullptr, nullptr, (float2*)H1, V, 0);
    layer_kernel<<<layer_blocks, 256, 0, stream>>>(
        offA, scolA, svalA, (const float2*)H1, (const float2*)Wt2,
        (const float2*)emb_W, norm_g, norm_b, (float2*)WS, V, 1);

    int doc_blocks = (D + 4 * RPW - 1) / (4 * RPW);
    doc_kernel<<<doc_blocks, 256, 0, stream>>>(
        offX, scolX, svalX, (const float2*)WS, (const float2*)Wt3,
        mlp_b, clf_W, clf_b, (float*)d_out, D);
}

// Round 2
// 761.548 us; speedup vs baseline: 1.5358x; 1.5358x over previous
//
#include <hip/hip_runtime.h>

#define RPW 4  // rows per wave in the fused row kernels

// ---- bf16 helpers: tables store 2 bf16 per uint (cols 2l, 2l+1) ------------
__device__ __forceinline__ float blo(unsigned u) { return __uint_as_float(u << 16); }
__device__ __forceinline__ float bhi(unsigned u) { return __uint_as_float(u & 0xffff0000u); }
__device__ __forceinline__ unsigned pack_bf16(float x, float y) {
    unsigned ux = __float_as_uint(x); ux += 0x7fffu + ((ux >> 16) & 1u);
    unsigned uy = __float_as_uint(y); uy += 0x7fffu + ((uy >> 16) & 1u);
    return (ux >> 16) | (uy & 0xffff0000u);
}

// ---------------------------------------------------------------------------
// Histogram of row indices for A and X.
// ---------------------------------------------------------------------------
__global__ void hist_kernel(const int* __restrict__ Arow, int nA,
                            const int* __restrict__ Xrow, int nX,
                            int* __restrict__ cntA, int* __restrict__ cntX) {
    int i = blockIdx.x * 256 + threadIdx.x;
    if (i < nA) {
        atomicAdd(&cntA[Arow[i]], 1);
    } else if (i < nA + nX) {
        atomicAdd(&cntX[Xrow[i - nA]], 1);
    }
}

// ---------------------------------------------------------------------------
// Hierarchical scan, stage 1: each block scans one 1024-chunk locally.
// off[i+1] = local inclusive, cnt[i] = local exclusive, chunkSums[b] = total.
// Blocks [0,nchA) cover A, [nchA, nchA+nchX) cover X.
// ---------------------------------------------------------------------------
__global__ __launch_bounds__(1024) void scan1_kernel(
    int* cntA, int* offA, int nA, int nchA,
    int* cntX, int* offX, int nX, int* chunkSums) {
    int b = blockIdx.x;
    int* cnt; int* off; int n; int cb;
    if (b < nchA) { cnt = cntA; off = offA; n = nA; cb = b; }
    else          { cnt = cntX; off = offX; n = nX; cb = b - nchA; }
    __shared__ int wsum[16];
    int tid = threadIdx.x, lane = tid & 63, w = tid >> 6;
    int i = cb * 1024 + tid;
    int x = (i < n) ? cnt[i] : 0;
    int v = x;
    #pragma unroll
    for (int d = 1; d < 64; d <<= 1) {
        int t = __shfl_up(v, d);
        if (lane >= d) v += t;
    }
    if (lane == 63) wsum[w] = v;
    __syncthreads();
    if (tid == 0) {
        int a = 0;
        #pragma unroll
        for (int j = 0; j < 16; ++j) { int t = wsum[j]; wsum[j] = a; a += t; }
        chunkSums[b] = a;
    }
    __syncthreads();
    int incl = v + wsum[w];
    if (i < n) { off[i + 1] = incl; cnt[i] = incl - x; }
}

// ---------------------------------------------------------------------------
// Stage 2: exclusive-scan the chunk totals. Wave 0 handles A's chunks,
// wave 1 handles X's chunks (robust to >64 chunks via carried loop).
// ---------------------------------------------------------------------------
__global__ __launch_bounds__(128) void scan2_kernel(int* chunkSums, int nchA, int nchX) {
    int lane = threadIdx.x & 63;
    int w = threadIdx.x >> 6;
    int n    = (w == 0) ? nchA : nchX;
    int base = (w == 0) ? 0 : nchA;
    int carry = 0;
    for (int s = 0; s < n; s += 64) {
        int v = (s + lane < n) ? chunkSums[base + s + lane] : 0;
        int incl = v;
        #pragma unroll
        for (int d = 1; d < 64; d <<= 1) {
            int t = __shfl_up(incl, d);
            if (lane >= d) incl += t;
        }
        int tot = __shfl(incl, 63);
        int ex = __shfl_up(incl, 1);
        if (lane == 0) ex = 0;
        if (s + lane < n) chunkSums[base + s + lane] = carry + ex;
        carry += tot;
    }
}

// ---------------------------------------------------------------------------
// Stage 3: add chunk bases -> global offsets; set off[0]=0.
// ---------------------------------------------------------------------------
__global__ void scan3_kernel(int* cntA, int* offA, int nA, int nchA,
                             int* cntX, int* offX, int nX,
                             const int* __restrict__ chunkSums) {
    int i = blockIdx.x * 256 + threadIdx.x;
    if (i < nA) {
        int b = chunkSums[i >> 10];
        cntA[i] += b; offA[i + 1] += b;
        if (i == 0) offA[0] = 0;
    } else {
        int j = i - nA;
        if (j < nX) {
            int b = chunkSums[nchA + (j >> 10)];
            cntX[j] += b; offX[j + 1] += b;
            if (j == 0) offX[0] = 0;
        }
    }
}

// ---------------------------------------------------------------------------
// Scatter COO -> CSR arrays using the cursor (counting sort by row).
// ---------------------------------------------------------------------------
__global__ void scatter_kernel(const int* __restrict__ Arow, const int* __restrict__ Acol,
                               const float* __restrict__ Aval, int nA,
                               const int* __restrict__ Xrow, const int* __restrict__ Xcol,
                               const float* __restrict__ Xval, int nX,
                               int* __restrict__ curA, int* __restrict__ scolA, float* __restrict__ svalA,
                               int* __restrict__ curX, int* __restrict__ scolX, float* __restrict__ svalX) {
    int i = blockIdx.x * 256 + threadIdx.x;
    if (i < nA) {
        int r = Arow[i];
        int p = atomicAdd(&curA[r], 1);
        scolA[p] = Acol[i];
        svalA[p] = Aval[i];
    } else if (i < nA + nX) {
        int j = i - nA;
        int r = Xrow[j];
        int p = atomicAdd(&curX[r], 1);
        scolX[p] = Xcol[j];
        svalX[p] = Xval[j];
    }
}

// ---------------------------------------------------------------------------
// Transpose the three 128x128 weight matrices (coalesced per-row GEMM reads)
// and convert emb_W to the packed-bf16 gather table.
// ---------------------------------------------------------------------------
__global__ void prep_kernel(const float* __restrict__ W1, const float* __restrict__ W2,
                            const float* __restrict__ W3,
                            float* __restrict__ Wt1, float* __restrict__ Wt2,
                            float* __restrict__ Wt3,
                            const float2* __restrict__ emb, unsigned* __restrict__ emb16,
                            int nemb) {   // nemb = V*64
    int gid = blockIdx.x * 256 + threadIdx.x;
    if (gid < 3 * 16384) {
        int m = gid >> 14;
        int idx = gid & 16383;
        int j = idx >> 7;
        int k = idx & 127;
        const float* W = (m == 0) ? W1 : (m == 1) ? W2 : W3;
        float*      Wt = (m == 0) ? Wt1 : (m == 1) ? Wt2 : Wt3;
        Wt[k * 128 + j] = W[j * 128 + k];
    }
    int e = gid - 3 * 16384;
    if (e >= 0 && e < nemb) {
        float2 f = emb[e];
        emb16[e] = pack_bf16(f.x, f.y);
    }
}

// ---------------------------------------------------------------------------
// Fused layer kernel. One wave owns RPW rows; lane l holds cols 2l, 2l+1.
// Gather table `in` is packed bf16 (uint per lane, row stride 64 uints).
//   mode 0: out = bf16(relu(spmm(A,in) @ W^T))
//   mode 1: t = relu(spmm(A,in) @ W^T); u = 0.3*emb + 0.7*t;
//           out = bf16(layernorm(u)*g + b + emb)   (word_H + emb_W pre-fused)
// Edge loop unrolled x4 for gather MLP. No __syncthreads in the hot path.
// ---------------------------------------------------------------------------
__global__ __launch_bounds__(256) void layer_kernel(
    const int* __restrict__ off, const int* __restrict__ scol, const float* __restrict__ sval,
    const unsigned* __restrict__ in,          // bf16-packed [nrows][64]
    const float2* __restrict__ Wt,            // [128][64] float2 view
    const float2* __restrict__ emb,           // fp32, mode 1 only
    const float* __restrict__ g, const float* __restrict__ bb,  // mode 1 only
    unsigned* __restrict__ out, int nrows, int mode) {

    __shared__ float acc_s[4][RPW][128];
    int lane = threadIdx.x & 63;
    int wave = threadIdx.x >> 6;
    int rowbase = (blockIdx.x * 4 + wave) * RPW;

    // --- SpMM: gather-reduce each row into wave-private LDS ---
    for (int r = 0; r < RPW; ++r) {
        int row = rowbase + r;
        float ax = 0.f, ay = 0.f;
        if (row < nrows) {
            int s = off[row], e = off[row + 1];
            int i = s;
            for (; i + 3 < e; i += 4) {
                int c0 = scol[i], c1 = scol[i + 1], c2 = scol[i + 2], c3 = scol[i + 3];
                float v0 = sval[i], v1 = sval[i + 1], v2 = sval[i + 2], v3 = sval[i + 3];
                unsigned x0 = in[(size_t)c0 * 64 + lane];
                unsigned x1 = in[(size_t)c1 * 64 + lane];
                unsigned x2 = in[(size_t)c2 * 64 + lane];
                unsigned x3 = in[(size_t)c3 * 64 + lane];
                ax += v0 * blo(x0) + v1 * blo(x1) + v2 * blo(x2) + v3 * blo(x3);
                ay += v0 * bhi(x0) + v1 * bhi(x1) + v2 * bhi(x2) + v3 * bhi(x3);
            }
            for (; i < e; ++i) {
                int c = scol[i];
                float v = sval[i];
                unsigned x = in[(size_t)c * 64 + lane];
                ax += v * blo(x);
                ay += v * bhi(x);
            }
        }
        *(float2*)&acc_s[wave][r][2 * lane] = make_float2(ax, ay);
    }

    // --- dense 128x128 GEMM: o[r][j] = sum_k acc[r][k] * Wt[k][j] ---
    float2 o[RPW];
    #pragma unroll
    for (int r = 0; r < RPW; ++r) o[r] = make_float2(0.f, 0.f);
    for (int k = 0; k < 128; k += 2) {
        float2 w0 = Wt[(size_t)k * 64 + lane];
        float2 w1 = Wt[(size_t)(k + 1) * 64 + lane];
        #pragma unroll
        for (int r = 0; r < RPW; ++r) {
            float a0 = acc_s[wave][r][k];
            float a1 = acc_s[wave][r][k + 1];
            o[r].x += a0 * w0.x + a1 * w1.x;
            o[r].y += a0 * w0.y + a1 * w1.y;
        }
    }

    // --- epilogue ---
    for (int r = 0; r < RPW; ++r) {
        int row = rowbase + r;
        if (row >= nrows) break;
        float hx = fmaxf(o[r].x, 0.f), hy = fmaxf(o[r].y, 0.f);
        if (mode == 0) {
            out[(size_t)row * 64 + lane] = pack_bf16(hx, hy);
        } else {
            float2 e2 = emb[(size_t)row * 64 + lane];
            float ux = 0.3f * e2.x + 0.7f * hx;
            float uy = 0.3f * e2.y + 0.7f * hy;
            float s = ux + uy;
            #pragma unroll
            for (int d = 1; d < 64; d <<= 1) s += __shfl_xor(s, d);
            float mu = s * (1.f / 128.f);
            float dx = ux - mu, dy = uy - mu;
            float q = dx * dx + dy * dy;
            #pragma unroll
            for (int d = 1; d < 64; d <<= 1) q += __shfl_xor(q, d);
            float rstd = rsqrtf(q * (1.f / 128.f) + 1e-5f);
            float2 gg = *(const float2*)&g[2 * lane];
            float2 b2 = *(const float2*)&bb[2 * lane];
            float wx = dx * rstd * gg.x + b2.x + e2.x;   // word_H + emb_W fused
            float wy = dy * rstd * gg.y + b2.y + e2.y;
            out[(size_t)row * 64 + lane] = pack_bf16(wx, wy);
        }
    }
}

// ---------------------------------------------------------------------------
// Doc kernel: spmm(X, word_sum[bf16]) -> relu(. @ mlp_W^T + b) -> clf logits.
// ---------------------------------------------------------------------------
__global__ __launch_bounds__(256) void doc_kernel(
    const int* __restrict__ off, const int* __restrict__ scol, const float* __restrict__ sval,
    const unsigned* __restrict__ in,          // bf16-packed word_sum [V][64]
    const float2* __restrict__ Wt,            // mlp_W transposed, float2 view
    const float* __restrict__ mlp_b, const float* __restrict__ clfW,
    const float* __restrict__ clfb,
    float* __restrict__ outp, int nrows) {

    __shared__ float acc_s[4][RPW][128];
    int lane = threadIdx.x & 63;
    int wave = threadIdx.x >> 6;
    int rowbase = (blockIdx.x * 4 + wave) * RPW;

    for (int r = 0; r < RPW; ++r) {
        int row = rowbase + r;
        float ax = 0.f, ay = 0.f;
        if (row < nrows) {
            int s = off[row], e = off[row + 1];
            int i = s;
            for (; i + 3 < e; i += 4) {
                int c0 = scol[i], c1 = scol[i + 1], c2 = scol[i + 2], c3 = scol[i + 3];
                float v0 = sval[i], v1 = sval[i + 1], v2 = sval[i + 2], v3 = sval[i + 3];
                unsigned x0 = in[(size_t)c0 * 64 + lane];
                unsigned x1 = in[(size_t)c1 * 64 + lane];
                unsigned x2 = in[(size_t)c2 * 64 + lane];
                unsigned x3 = in[(size_t)c3 * 64 + lane];
                ax += v0 * blo(x0) + v1 * blo(x1) + v2 * blo(x2) + v3 * blo(x3);
                ay += v0 * bhi(x0) + v1 * bhi(x1) + v2 * bhi(x2) + v3 * bhi(x3);
            }
            for (; i < e; ++i) {
                int c = scol[i];
                float v = sval[i];
                unsigned x = in[(size_t)c * 64 + lane];
                ax += v * blo(x);
                ay += v * bhi(x);
            }
        }
        *(float2*)&acc_s[wave][r][2 * lane] = make_float2(ax, ay);
    }

    float2 o[RPW];
    #pragma unroll
    for (int r = 0; r < RPW; ++r) o[r] = make_float2(0.f, 0.f);
    for (int k = 0; k < 128; k += 2) {
        float2 w0 = Wt[(size_t)k * 64 + lane];
        float2 w1 = Wt[(size_t)(k + 1) * 64 + lane];
        #pragma unroll
        for (int r = 0; r < RPW; ++r) {
            float a0 = acc_s[wave][r][k];
            float a1 = acc_s[wave][r][k + 1];
            o[r].x += a0 * w0.x + a1 * w1.x;
            o[r].y += a0 * w0.y + a1 * w1.y;
        }
    }

    float2 mb = *(const float2*)&mlp_b[2 * lane];
    float2 c0 = *(const float2*)&clfW[2 * lane];
    float2 c1 = *(const float2*)&clfW[128 + 2 * lane];
    for (int r = 0; r < RPW; ++r) {
        int row = rowbase + r;
        if (row >= nrows) break;
        float hx = fmaxf(o[r].x + mb.x, 0.f);
        float hy = fmaxf(o[r].y + mb.y, 0.f);
        float p0 = hx * c0.x + hy * c0.y;
        float p1 = hx * c1.x + hy * c1.y;
        #pragma unroll
        for (int d = 1; d < 64; d <<= 1) {
            p0 += __shfl_xor(p0, d);
            p1 += __shfl_xor(p1, d);
        }
        if (lane == 0) {
            outp[(size_t)row * 2 + 0] = p0 + clfb[0];
            outp[(size_t)row * 2 + 1] = p1 + clfb[1];
        }
    }
}

// ---------------------------------------------------------------------------
extern "C" void kernel_launch(void* const* d_in, const int* in_sizes, int n_in,
                              void* d_out, int out_size, void* d_ws, size_t ws_size,
                              hipStream_t stream) {
    const int*   A_row  = (const int*)d_in[0];
    const int*   A_col  = (const int*)d_in[1];
    const float* A_val  = (const float*)d_in[2];
    const int*   X_row  = (const int*)d_in[3];
    const int*   X_col  = (const int*)d_in[4];
    const float* X_val  = (const float*)d_in[5];
    const float* emb_W  = (const float*)d_in[6];
    const float* lin1_W = (const float*)d_in[7];
    const float* lin2_W = (const float*)d_in[8];
    const float* norm_g = (const float*)d_in[9];
    const float* norm_b = (const float*)d_in[10];
    const float* mlp_W  = (const float*)d_in[11];
    const float* mlp_b  = (const float*)d_in[12];
    const float* clf_W  = (const float*)d_in[13];
    const float* clf_b  = (const float*)d_in[14];

    const int E   = in_sizes[0];
    const int NNZ = in_sizes[3];
    const int V   = in_sizes[6] / 128;
    const int D   = out_size / 2;   // N_DOCS
    const int nchA = (V + 1023) / 1024;
    const int nchX = (D + 1023) / 1024;

    // workspace carve-up (256B aligned)
    char* p = (char*)d_ws;
    auto alloc = [&](size_t bytes) -> void* {
        void* q = (void*)p;
        p += (bytes + 255) & ~(size_t)255;
        return q;
    };
    int*      curA   = (int*)alloc((size_t)V * 4);
    int*      offA   = (int*)alloc((size_t)(V + 1) * 4);
    int*      scolA  = (int*)alloc((size_t)E * 4);
    float*    svalA  = (float*)alloc((size_t)E * 4);
    int*      curX   = (int*)alloc((size_t)D * 4);
    int*      offX   = (int*)alloc((size_t)(D + 1) * 4);
    int*      scolX  = (int*)alloc((size_t)NNZ * 4);
    float*    svalX  = (float*)alloc((size_t)NNZ * 4);
    int*      chunkS = (int*)alloc((size_t)(nchA + nchX) * 4);
    float*    Wt1    = (float*)alloc(128 * 128 * 4);
    float*    Wt2    = (float*)alloc(128 * 128 * 4);
    float*    Wt3    = (float*)alloc(128 * 128 * 4);
    unsigned* EMB16  = (unsigned*)alloc((size_t)V * 64 * 4);  // bf16-packed emb
    unsigned* H1     = (unsigned*)alloc((size_t)V * 64 * 4);  // bf16-packed
    unsigned* WS     = (unsigned*)alloc((size_t)V * 64 * 4);  // bf16-packed word_H+emb

    hipMemsetAsync(curA, 0, (size_t)V * 4, stream);
    hipMemsetAsync(curX, 0, (size_t)D * 4, stream);

    int tot = E + NNZ;
    hist_kernel<<<(tot + 255) / 256, 256, 0, stream>>>(A_row, E, X_row, NNZ, curA, curX);
    scan1_kernel<<<nchA + nchX, 1024, 0, stream>>>(curA, offA, V, nchA, curX, offX, D, chunkS);
    scan2_kernel<<<1, 128, 0, stream>>>(chunkS, nchA, nchX);
    scan3_kernel<<<(V + D + 255) / 256, 256, 0, stream>>>(curA, offA, V, nchA, curX, offX, D, chunkS);
    scatter_kernel<<<(tot + 255) / 256, 256, 0, stream>>>(
        A_row, A_col, A_val, E, X_row, X_col, X_val, NNZ,
        curA, scolA, svalA, curX, scolX, svalX);
    prep_kernel<<<(3 * 16384 + V * 64 + 255) / 256, 256, 0, stream>>>(
        lin1_W, lin2_W, mlp_W, Wt1, Wt2, Wt3, (const float2*)emb_W, EMB16, V * 64);

    int layer_blocks = (V + 4 * RPW - 1) / (4 * RPW);
    layer_kernel<<<layer_blocks, 256, 0, stream>>>(
        offA, scolA, svalA, EMB16, (const float2*)Wt1,
        nullptr, nullptr, nullptr, H1, V, 0);
    layer_kernel<<<layer_blocks, 256, 0, stream>>>(
        offA, scolA, svalA, H1, (const float2*)Wt2,
        (const float2*)emb_W, norm_g, norm_b, WS, V, 1);

    int doc_blocks = (D + 4 * RPW - 1) / (4 * RPW);
    doc_kernel<<<doc_blocks, 256, 0, stream>>>(
        offX, scolX, svalX, WS, (const float2*)Wt3,
        mlp_b, clf_W, clf_b, (float*)d_out, D);
}